// Round 1
// baseline (1497.157 us; speedup 1.0000x reference)
//
#include <hip/hip_runtime.h>
#include <math.h>

// Problem constants
constexpr int Bc  = 8;
constexpr int Nn  = 1024;
constexpr int Dd  = 512;
constexpr int Hh  = 8;
constexpr int HD  = 64;
constexpr int QT  = 8;          // q rows per attention block
constexpr float SCALE = 0.125f; // 1/sqrt(64)

// node_valid_mask may arrive as 1-byte bool or 4-byte int/float.
// Detect: byte[1] is the second byte; for 1-byte layout it's mask[0][1]=1,
// for 4-byte layouts it's a high byte of element 0 (=0).
__device__ __forceinline__ bool lane_valid(const unsigned char* m8, bool bytelay, int idx) {
  if (bytelay) return m8[idx] != 0;
  return ((const int*)m8)[idx] != 0;   // covers int32 (0/1) and fp32 (0x3F800000)
}

// ---------------------------------------------------------------------------
// Generic fp32 GEMM: C[M x Ncols] = A[M x 512] * W[Ncols x 512]^T + bias[Ncols]
// Tile 64x64, BK=16, 256 threads, 4x4 per thread. SCATTER=true writes the
// qkv projection directly into q/k/v buffers laid out [B,H,N,HD].
// ---------------------------------------------------------------------------
template<bool SCATTER>
__global__ __launch_bounds__(256) void gemm_k512(
    const float* __restrict__ A, const float* __restrict__ W,
    const float* __restrict__ bias, float* __restrict__ C,
    float* __restrict__ qb, float* __restrict__ kb, float* __restrict__ vb,
    int Ncols)
{
  __shared__ float Ast[16][68];   // [k][row], pad 68 -> 16B-aligned rows
  __shared__ float Wst[16][68];   // [k][col]

  const int t  = threadIdx.x;
  const int tx = t & 15, ty = t >> 4;
  const int i0 = blockIdx.y * 64, j0 = blockIdx.x * 64;
  const int r  = t >> 2;          // 0..63 staging row
  const int c4 = (t & 3) * 4;     // 0,4,8,12 staging k-offset

  float acc[4][4];
#pragma unroll
  for (int a = 0; a < 4; ++a)
#pragma unroll
    for (int b2 = 0; b2 < 4; ++b2) acc[a][b2] = 0.f;

  const float* Aptr = A + (size_t)(i0 + r) * 512 + c4;
  const float* Wptr = W + (size_t)(j0 + r) * 512 + c4;

  for (int kt = 0; kt < 32; ++kt) {
    float4 a4 = *(const float4*)(Aptr + kt * 16);
    float4 w4 = *(const float4*)(Wptr + kt * 16);
    __syncthreads();
    Ast[c4 + 0][r] = a4.x; Ast[c4 + 1][r] = a4.y; Ast[c4 + 2][r] = a4.z; Ast[c4 + 3][r] = a4.w;
    Wst[c4 + 0][r] = w4.x; Wst[c4 + 1][r] = w4.y; Wst[c4 + 2][r] = w4.z; Wst[c4 + 3][r] = w4.w;
    __syncthreads();
#pragma unroll
    for (int kk = 0; kk < 16; ++kk) {
      float4 av = *(const float4*)&Ast[kk][ty * 4];
      float4 wv = *(const float4*)&Wst[kk][tx * 4];
      float aa[4] = {av.x, av.y, av.z, av.w};
      float ww[4] = {wv.x, wv.y, wv.z, wv.w};
#pragma unroll
      for (int ii = 0; ii < 4; ++ii)
#pragma unroll
        for (int jj = 0; jj < 4; ++jj)
          acc[ii][jj] += aa[ii] * ww[jj];
    }
  }

  float4 bv = *(const float4*)&bias[j0 + tx * 4];
  float ba[4] = {bv.x, bv.y, bv.z, bv.w};

  if (SCATTER) {
    const int s = j0 >> 9;              // 0=q 1=k 2=v
    const int h = (j0 >> 6) & 7;        // head
    float* dst = (s == 0) ? qb : (s == 1) ? kb : vb;
#pragma unroll
    for (int ii = 0; ii < 4; ++ii) {
      const int i = i0 + ty * 4 + ii;
      const int b2 = i >> 10, n = i & 1023;
      float4 o;
      o.x = acc[ii][0] + ba[0]; o.y = acc[ii][1] + ba[1];
      o.z = acc[ii][2] + ba[2]; o.w = acc[ii][3] + ba[3];
      *(float4*)&dst[(((size_t)(b2 * Hh + h)) * Nn + n) * HD + tx * 4] = o;
    }
  } else {
#pragma unroll
    for (int ii = 0; ii < 4; ++ii) {
      const int i = i0 + ty * 4 + ii;
      float4 o;
      o.x = acc[ii][0] + ba[0]; o.y = acc[ii][1] + ba[1];
      o.z = acc[ii][2] + ba[2]; o.w = acc[ii][3] + ba[3];
      *(float4*)&C[(size_t)i * Ncols + j0 + tx * 4] = o;
    }
  }
}

// ---------------------------------------------------------------------------
// Attention: one block = one (b,h) x 8-query-row tile. Full 1024 score row in
// LDS, key-masked -inf, per-row softmax (32 lanes/row), then P*V with staged
// V tiles. Invalid query rows zeroed via final scale (matches nan_to_num).
// ---------------------------------------------------------------------------
__global__ __launch_bounds__(256) void attn_k(
    const float* __restrict__ qg, const float* __restrict__ kg,
    const float* __restrict__ vg, const float* __restrict__ bias,
    const unsigned char* __restrict__ m8, float* __restrict__ outp)
{
  __shared__ float qs[QT * 64];        // 2 KB
  __shared__ float Kst[64][66];        // transposed K tile [d][k], 16.9 KB
  __shared__ float Vs[64 * 68];        // V tile [k][d] pad 68, 17.4 KB
  __shared__ float Ss[QT][1024];       // score rows, 32 KB
  __shared__ float rowmax[QT], rowsum[QT];

  const int t   = threadIdx.x;
  const int blk = blockIdx.x;
  const int qt  = blk & 127;           // N/QT = 128 tiles
  const int bh  = blk >> 7;            // 0..63
  const int b   = bh >> 3;
  const int h   = bh & 7;
  const int q0  = qt * QT;
  const bool bytelay = (m8[1] != 0);

  // stage q tile (512 consecutive floats)
  {
    const float* src = qg + ((size_t)bh * Nn + q0) * 64;
    *(float2*)&qs[t * 2] = *(const float2*)&src[t * 2];
  }

  const int qi = t >> 5;               // 0..7 row
  const int k0 = (t & 31) * 2;         // 2 keys per thread

  // ---- scores ----
  for (int kt = 0; kt < 16; ++kt) {
    __syncthreads();
#pragma unroll
    for (int i = 0; i < 4; ++i) {      // stage K tile transposed
      const int idx = i * 256 + t;
      const int kk  = idx >> 4;
      const int d4  = (idx & 15) * 4;
      float4 kv = *(const float4*)&kg[((size_t)bh * Nn + kt * 64 + kk) * 64 + d4];
      Kst[d4 + 0][kk] = kv.x; Kst[d4 + 1][kk] = kv.y;
      Kst[d4 + 2][kk] = kv.z; Kst[d4 + 3][kk] = kv.w;
    }
    __syncthreads();
    float sx = 0.f, sy = 0.f;
#pragma unroll 16
    for (int d = 0; d < 64; ++d) {
      float qv = qs[qi * 64 + d];
      float2 kk2 = *(const float2*)&Kst[d][k0];
      sx += qv * kk2.x; sy += qv * kk2.y;
    }
    const int kglob = kt * 64 + k0;
    float2 bb = *(const float2*)&bias[((size_t)bh * Nn + (q0 + qi)) * Nn + kglob];
    const bool v0 = lane_valid(m8, bytelay, b * Nn + kglob);
    const bool v1 = lane_valid(m8, bytelay, b * Nn + kglob + 1);
    float2 so;
    so.x = v0 ? sx * SCALE + bb.x : -__builtin_inff();
    so.y = v1 ? sy * SCALE + bb.y : -__builtin_inff();
    *(float2*)&Ss[qi][kglob] = so;
  }
  __syncthreads();

  // ---- softmax (32 lanes per row) ----
  {
    const int row = t >> 5, l = t & 31;
    float m = -__builtin_inff();
#pragma unroll
    for (int j = 0; j < 32; ++j) m = fmaxf(m, Ss[row][l + 32 * j]);
#pragma unroll
    for (int off = 16; off; off >>= 1) m = fmaxf(m, __shfl_xor(m, off, 32));
    if (l == 0) rowmax[row] = m;
    __syncthreads();
    m = rowmax[row];                   // finite: valid keys always exist
    float sum = 0.f;
#pragma unroll
    for (int j = 0; j < 32; ++j) {
      const int c = l + 32 * j;
      float e = __expf(Ss[row][c] - m);   // exp(-inf)=0 for masked keys
      Ss[row][c] = e;
      sum += e;
    }
#pragma unroll
    for (int off = 16; off; off >>= 1) sum += __shfl_xor(sum, off, 32);
    if (l == 0) rowsum[row] = sum;
  }

  // ---- P * V ----
  const int d0 = (t & 31) * 2;
  float ax = 0.f, ay = 0.f;
  for (int kt = 0; kt < 16; ++kt) {
    __syncthreads();
#pragma unroll
    for (int i = 0; i < 4; ++i) {      // stage V tile
      const int idx = i * 256 + t;
      const int kk  = idx >> 4;
      const int d4  = (idx & 15) * 4;
      *(float4*)&Vs[kk * 68 + d4] =
          *(const float4*)&vg[((size_t)bh * Nn + kt * 64 + kk) * 64 + d4];
    }
    __syncthreads();
#pragma unroll 16
    for (int k = 0; k < 64; ++k) {
      float p = Ss[qi][kt * 64 + k];
      float2 vv = *(const float2*)&Vs[k * 68 + d0];
      ax += p * vv.x; ay += p * vv.y;
    }
  }

  const bool vq = lane_valid(m8, bytelay, b * Nn + q0 + qi);
  const float rinv = vq ? (1.0f / rowsum[qi]) : 0.f;
  float2 o; o.x = ax * rinv; o.y = ay * rinv;
  // attn output in [B, N, H*HD] layout (ready for out-projection)
  *(float2*)&outp[((size_t)(b * Nn + q0 + qi)) * Dd + h * 64 + d0] = o;
}

// ---------------------------------------------------------------------------
extern "C" void kernel_launch(void* const* d_in, const int* in_sizes, int n_in,
                              void* d_out, int out_size, void* d_ws, size_t ws_size,
                              hipStream_t stream) {
  const float* x        = (const float*)d_in[0];
  const unsigned char* mask8 = (const unsigned char*)d_in[1];
  const float* attnbias = (const float*)d_in[2];
  const float* qkv_w    = (const float*)d_in[3];
  const float* qkv_b    = (const float*)d_in[4];
  const float* out_w    = (const float*)d_in[5];
  const float* out_b    = (const float*)d_in[6];
  float* out = (float*)d_out;

  float* ws   = (float*)d_ws;
  const size_t SEG = (size_t)Bc * Hh * Nn * HD;   // 4,194,304 floats = 16 MB
  float* qbuf = ws;
  float* kbuf = ws + SEG;
  float* vbuf = ws + 2 * SEG;
  float* aout = ws + 3 * SEG;                     // [B,N,D]

  // 1) QKV projection, scattered into q/k/v [B,H,N,HD]
  gemm_k512<true><<<dim3(1536 / 64, 8192 / 64), 256, 0, stream>>>(
      x, qkv_w, qkv_b, nullptr, qbuf, kbuf, vbuf, 1536);

  // 2) attention -> aout [B,N,D]
  attn_k<<<dim3(Bc * Hh * (Nn / QT)), 256, 0, stream>>>(
      qbuf, kbuf, vbuf, attnbias, mask8, aout);

  // 3) output projection -> d_out
  gemm_k512<false><<<dim3(512 / 64, 8192 / 64), 256, 0, stream>>>(
      aout, out_w, out_b, out, nullptr, nullptr, nullptr, 512);
}

// Round 2
// 756.901 us; speedup vs baseline: 1.9780x; 1.9780x over previous
//
#include <hip/hip_runtime.h>
#include <math.h>

// Problem constants
constexpr int Bc  = 8;
constexpr int Nn  = 1024;
constexpr int Dd  = 512;
constexpr int Hh  = 8;
constexpr int HD  = 64;
constexpr float SCALE = 0.125f; // 1/sqrt(64)

// node_valid_mask may arrive as 1-byte bool or 4-byte int/float.
// Detect: byte[1] is mask[0][1]=1 for 1-byte layout, a zero high byte for 4-byte.
__device__ __forceinline__ bool lane_valid(const unsigned char* m8, bool bytelay, int idx) {
  if (bytelay) return m8[idx] != 0;
  return ((const int*)m8)[idx] != 0;   // covers int32 (0/1) and fp32 (0x3F800000)
}

// ---------------------------------------------------------------------------
// Generic fp32 GEMM: C[M x Ncols] = A[M x 512] * W[Ncols x 512]^T + bias[Ncols]
// Tile 64x64, BK=16, 256 threads, 4x4 per thread. SCATTER=true writes the
// qkv projection directly into q/k/v buffers laid out [B,H,N,HD].
// ---------------------------------------------------------------------------
template<bool SCATTER>
__global__ __launch_bounds__(256) void gemm_k512(
    const float* __restrict__ A, const float* __restrict__ W,
    const float* __restrict__ bias, float* __restrict__ C,
    float* __restrict__ qb, float* __restrict__ kb, float* __restrict__ vb,
    int Ncols)
{
  __shared__ float Ast[16][68];   // [k][row]
  __shared__ float Wst[16][68];   // [k][col]

  const int t  = threadIdx.x;
  const int tx = t & 15, ty = t >> 4;
  const int i0 = blockIdx.y * 64, j0 = blockIdx.x * 64;
  const int r  = t >> 2;
  const int c4 = (t & 3) * 4;

  float acc[4][4];
#pragma unroll
  for (int a = 0; a < 4; ++a)
#pragma unroll
    for (int b2 = 0; b2 < 4; ++b2) acc[a][b2] = 0.f;

  const float* Aptr = A + (size_t)(i0 + r) * 512 + c4;
  const float* Wptr = W + (size_t)(j0 + r) * 512 + c4;

  for (int kt = 0; kt < 32; ++kt) {
    float4 a4 = *(const float4*)(Aptr + kt * 16);
    float4 w4 = *(const float4*)(Wptr + kt * 16);
    __syncthreads();
    Ast[c4 + 0][r] = a4.x; Ast[c4 + 1][r] = a4.y; Ast[c4 + 2][r] = a4.z; Ast[c4 + 3][r] = a4.w;
    Wst[c4 + 0][r] = w4.x; Wst[c4 + 1][r] = w4.y; Wst[c4 + 2][r] = w4.z; Wst[c4 + 3][r] = w4.w;
    __syncthreads();
#pragma unroll
    for (int kk = 0; kk < 16; ++kk) {
      float4 av = *(const float4*)&Ast[kk][ty * 4];
      float4 wv = *(const float4*)&Wst[kk][tx * 4];
      float aa[4] = {av.x, av.y, av.z, av.w};
      float ww[4] = {wv.x, wv.y, wv.z, wv.w};
#pragma unroll
      for (int ii = 0; ii < 4; ++ii)
#pragma unroll
        for (int jj = 0; jj < 4; ++jj)
          acc[ii][jj] += aa[ii] * ww[jj];
    }
  }

  float4 bv = *(const float4*)&bias[j0 + tx * 4];
  float ba[4] = {bv.x, bv.y, bv.z, bv.w};

  if (SCATTER) {
    const int s = j0 >> 9;
    const int h = (j0 >> 6) & 7;
    float* dst = (s == 0) ? qb : (s == 1) ? kb : vb;
#pragma unroll
    for (int ii = 0; ii < 4; ++ii) {
      const int i = i0 + ty * 4 + ii;
      const int b2 = i >> 10, n = i & 1023;
      float4 o;
      o.x = acc[ii][0] + ba[0]; o.y = acc[ii][1] + ba[1];
      o.z = acc[ii][2] + ba[2]; o.w = acc[ii][3] + ba[3];
      *(float4*)&dst[(((size_t)(b2 * Hh + h)) * Nn + n) * HD + tx * 4] = o;
    }
  } else {
#pragma unroll
    for (int ii = 0; ii < 4; ++ii) {
      const int i = i0 + ty * 4 + ii;
      float4 o;
      o.x = acc[ii][0] + ba[0]; o.y = acc[ii][1] + ba[1];
      o.z = acc[ii][2] + ba[2]; o.w = acc[ii][3] + ba[3];
      *(float4*)&C[(size_t)i * Ncols + j0 + tx * 4] = o;
    }
  }
}

// ---------------------------------------------------------------------------
// Flash-style attention. One block = one (b,h) x 64-query tile, 256 threads.
// Per K-tile (64 keys): stage K^T and V in LDS, 4x4 outer-product S = Q*K^T,
// online softmax in registers, P (transposed, unioned with K buffer) * V
// outer-product into O registers. Fully-masked key tiles are skipped.
// LDS = 3 x 64x68 floats = 52 KB -> 3 blocks/CU.
// ---------------------------------------------------------------------------
__global__ __launch_bounds__(256) void attn_k(
    const float* __restrict__ qg, const float* __restrict__ kg,
    const float* __restrict__ vg, const float* __restrict__ bias,
    const unsigned char* __restrict__ m8, float* __restrict__ outp)
{
  __shared__ float Qst[64][68];  // [d][q]
  __shared__ float KP[64][68];   // K-phase: [d][k]; P-phase: [k][q]
  __shared__ float Vst[64][68];  // [k][d]

  const int t  = threadIdx.x;
  const int tx = t & 15;         // k-group (S) / d-group (PV)
  const int ty = t >> 4;         // q-group: rows ty*4 .. ty*4+3
  const int bx = blockIdx.x;
  const int qt = bx & 15;
  const int bh = bx >> 4;        // 0..63
  const int b  = bh >> 3;
  const int h  = bh & 7;
  const int q0 = qt * 64;
  const bool bytelay = (m8[1] != 0);

  // stage Q transposed: Qst[d][q]
#pragma unroll
  for (int i = 0; i < 4; ++i) {
    const int idx = i * 256 + t;
    const int qq  = idx >> 4;
    const int d4  = (idx & 15) * 4;
    float4 v = *(const float4*)&qg[((size_t)bh * Nn + q0 + qq) * HD + d4];
    Qst[d4 + 0][qq] = v.x; Qst[d4 + 1][qq] = v.y;
    Qst[d4 + 2][qq] = v.z; Qst[d4 + 3][qq] = v.w;
  }

  float O[4][4];
  float m_run[4], l_run[4];
#pragma unroll
  for (int ii = 0; ii < 4; ++ii) {
    m_run[ii] = -__builtin_inff(); l_run[ii] = 0.f;
#pragma unroll
    for (int jj = 0; jj < 4; ++jj) O[ii][jj] = 0.f;
  }

  for (int kt = 0; kt < 16; ++kt) {
    // key-validity for this thread's 4 keys; skip fully-masked tiles.
    bool kv[4]; int any = 0;
#pragma unroll
    for (int jj = 0; jj < 4; ++jj) {
      kv[jj] = lane_valid(m8, bytelay, b * Nn + kt * 64 + 4 * tx + jj);
      any |= (int)kv[jj];
    }
    // barrier: also protects KP/Vst against the previous tile's PV reads
    if (!__syncthreads_or(any)) continue;

    // stage K (transposed) and V
#pragma unroll
    for (int i = 0; i < 4; ++i) {
      const int idx = i * 256 + t;
      const int kk  = idx >> 4;
      const int d4  = (idx & 15) * 4;
      float4 kvv = *(const float4*)&kg[((size_t)bh * Nn + kt * 64 + kk) * HD + d4];
      KP[d4 + 0][kk] = kvv.x; KP[d4 + 1][kk] = kvv.y;
      KP[d4 + 2][kk] = kvv.z; KP[d4 + 3][kk] = kvv.w;
      *(float4*)&Vst[kk][d4] =
          *(const float4*)&vg[((size_t)bh * Nn + kt * 64 + kk) * HD + d4];
    }
    __syncthreads();

    // bias prefetch (global; latency hidden under the S loop)
    float4 bias4[4];
#pragma unroll
    for (int ii = 0; ii < 4; ++ii)
      bias4[ii] = *(const float4*)
          &bias[((size_t)bh * Nn + q0 + 4 * ty + ii) * Nn + kt * 64 + 4 * tx];

    // S = Q * K^T, 4x4 outer product per thread
    float S[4][4];
#pragma unroll
    for (int ii = 0; ii < 4; ++ii)
#pragma unroll
      for (int jj = 0; jj < 4; ++jj) S[ii][jj] = 0.f;
#pragma unroll 4
    for (int d = 0; d < 64; ++d) {
      float4 q4 = *(const float4*)&Qst[d][4 * ty];
      float4 k4 = *(const float4*)&KP[d][4 * tx];
      float qa[4] = {q4.x, q4.y, q4.z, q4.w};
      float ka[4] = {k4.x, k4.y, k4.z, k4.w};
#pragma unroll
      for (int ii = 0; ii < 4; ++ii)
#pragma unroll
        for (int jj = 0; jj < 4; ++jj)
          S[ii][jj] += qa[ii] * ka[jj];
    }

    // scale + bias + key mask; per-row tile max
    float mt[4];
#pragma unroll
    for (int ii = 0; ii < 4; ++ii) {
      float bb[4] = {bias4[ii].x, bias4[ii].y, bias4[ii].z, bias4[ii].w};
      float m = -__builtin_inff();
#pragma unroll
      for (int jj = 0; jj < 4; ++jj) {
        float s = kv[jj] ? S[ii][jj] * SCALE + bb[jj] : -__builtin_inff();
        S[ii][jj] = s;
        m = fmaxf(m, s);
      }
      mt[ii] = m;
    }
    // reduce max across the 16 tx lanes (xor butterfly stays in-group)
#pragma unroll
    for (int off = 1; off < 16; off <<= 1)
#pragma unroll
      for (int ii = 0; ii < 4; ++ii)
        mt[ii] = fmaxf(mt[ii], __shfl_xor(mt[ii], off));

    // online-softmax update
    float alpha[4], lt[4];
#pragma unroll
    for (int ii = 0; ii < 4; ++ii) {
      float mn = fmaxf(m_run[ii], mt[ii]);   // finite: tile has a valid key
      alpha[ii] = __expf(m_run[ii] - mn);    // exp(-inf)=0 on first tile
      m_run[ii] = mn;
      float l = 0.f;
#pragma unroll
      for (int jj = 0; jj < 4; ++jj) {
        float p = __expf(S[ii][jj] - mn);    // masked: exp(-inf)=0
        S[ii][jj] = p;
        l += p;
      }
      lt[ii] = l;
    }
#pragma unroll
    for (int off = 1; off < 16; off <<= 1)
#pragma unroll
      for (int ii = 0; ii < 4; ++ii)
        lt[ii] += __shfl_xor(lt[ii], off);
#pragma unroll
    for (int ii = 0; ii < 4; ++ii) {
      l_run[ii] = l_run[ii] * alpha[ii] + lt[ii];
#pragma unroll
      for (int jj = 0; jj < 4; ++jj) O[ii][jj] *= alpha[ii];
    }

    __syncthreads();               // all Kst reads done; safe to overwrite
    // write P transposed into KP: KP[k][q]
#pragma unroll
    for (int jj = 0; jj < 4; ++jj) {
      float4 p4; p4.x = S[0][jj]; p4.y = S[1][jj]; p4.z = S[2][jj]; p4.w = S[3][jj];
      *(float4*)&KP[4 * tx + jj][4 * ty] = p4;
    }
    __syncthreads();

    // O += P * V, 4x4 outer product per thread
#pragma unroll 4
    for (int k = 0; k < 64; ++k) {
      float4 p4 = *(const float4*)&KP[k][4 * ty];
      float4 v4 = *(const float4*)&Vst[k][4 * tx];
      float pa[4] = {p4.x, p4.y, p4.z, p4.w};
      float va[4] = {v4.x, v4.y, v4.z, v4.w};
#pragma unroll
      for (int ii = 0; ii < 4; ++ii)
#pragma unroll
        for (int jj = 0; jj < 4; ++jj)
          O[ii][jj] += pa[ii] * va[jj];
    }
  }

  // epilogue: normalize; invalid/fully-masked query rows -> 0 (nan_to_num)
#pragma unroll
  for (int ii = 0; ii < 4; ++ii) {
    const int q = q0 + 4 * ty + ii;
    const bool vq = lane_valid(m8, bytelay, b * Nn + q);
    const float r = (vq && l_run[ii] > 0.f) ? (1.f / l_run[ii]) : 0.f;
    float4 o;
    o.x = O[ii][0] * r; o.y = O[ii][1] * r;
    o.z = O[ii][2] * r; o.w = O[ii][3] * r;
    *(float4*)&outp[((size_t)(b * Nn + q)) * Dd + h * HD + 4 * tx] = o;
  }
}

// ---------------------------------------------------------------------------
extern "C" void kernel_launch(void* const* d_in, const int* in_sizes, int n_in,
                              void* d_out, int out_size, void* d_ws, size_t ws_size,
                              hipStream_t stream) {
  const float* x        = (const float*)d_in[0];
  const unsigned char* mask8 = (const unsigned char*)d_in[1];
  const float* attnbias = (const float*)d_in[2];
  const float* qkv_w    = (const float*)d_in[3];
  const float* qkv_b    = (const float*)d_in[4];
  const float* out_w    = (const float*)d_in[5];
  const float* out_b    = (const float*)d_in[6];
  float* out = (float*)d_out;

  float* ws   = (float*)d_ws;
  const size_t SEG = (size_t)Bc * Hh * Nn * HD;   // 16 MB each
  float* qbuf = ws;
  float* kbuf = ws + SEG;
  float* vbuf = ws + 2 * SEG;
  float* aout = ws + 3 * SEG;                     // [B,N,D]

  // 1) QKV projection, scattered into q/k/v [B,H,N,HD]
  gemm_k512<true><<<dim3(1536 / 64, 8192 / 64), 256, 0, stream>>>(
      x, qkv_w, qkv_b, nullptr, qbuf, kbuf, vbuf, 1536);

  // 2) attention -> aout [B,N,D]
  attn_k<<<dim3(Bc * Hh * (Nn / 64)), 256, 0, stream>>>(
      qbuf, kbuf, vbuf, attnbias, mask8, aout);

  // 3) output projection -> d_out
  gemm_k512<false><<<dim3(512 / 64, 8192 / 64), 256, 0, stream>>>(
      aout, out_w, out_b, out, nullptr, nullptr, nullptr, 512);
}

// Round 3
// 652.164 us; speedup vs baseline: 2.2957x; 1.1606x over previous
//
#include <hip/hip_runtime.h>
#include <math.h>

// Problem constants
constexpr int Bc  = 8;
constexpr int Nn  = 1024;
constexpr int Dd  = 512;
constexpr int Hh  = 8;
constexpr int HD  = 64;
constexpr float SCALE = 0.125f; // 1/sqrt(64)

typedef unsigned short ushort_t;
typedef unsigned int uint32;
typedef __attribute__((ext_vector_type(8))) short short8;   // 8 bf16 (4 VGPRs)
typedef __attribute__((ext_vector_type(4))) float f32x4;

// ---------------- bf16 split helpers (round-to-nearest-even) ----------------
__device__ __forceinline__ uint32 bf16rn(float x) {
  uint32 u = __float_as_uint(x);
  return (u + 0x7FFFu + ((u >> 16) & 1u)) >> 16;
}
__device__ __forceinline__ float bf16up(uint32 h) { return __uint_as_float(h << 16); }

__device__ __forceinline__ void split8(const float* xs, uint4& hi, uint4& lo) {
  uint32 h[8], l[8];
#pragma unroll
  for (int j = 0; j < 8; ++j) {
    h[j] = bf16rn(xs[j]);
    l[j] = bf16rn(xs[j] - bf16up(h[j]));
  }
  hi.x = h[0] | (h[1] << 16); hi.y = h[2] | (h[3] << 16);
  hi.z = h[4] | (h[5] << 16); hi.w = h[6] | (h[7] << 16);
  lo.x = l[0] | (l[1] << 16); lo.y = l[2] | (l[3] << 16);
  lo.z = l[4] | (l[5] << 16); lo.w = l[6] | (l[7] << 16);
}

// node_valid_mask may arrive as 1-byte bool or 4-byte int/float.
__device__ __forceinline__ bool lane_valid(const unsigned char* m8, bool bytelay, int idx) {
  if (bytelay) return m8[idx] != 0;
  return ((const int*)m8)[idx] != 0;
}

// ---------------------------------------------------------------------------
// Convert fp32 [8192][512] -> MFMA-fragment-tiled split bf16:
// layout [R/16 rowtiles][16 ksteps][2 hi/lo][64 lanes * 8] ushort.
// Lane l of fragment (rt,ks) holds src[rt*16 + (l&15)][ks*32 + (l>>4)*8 + j].
// One thread = one lane-run (8 elems). Writes are wave-contiguous 1 KB.
// ---------------------------------------------------------------------------
__global__ __launch_bounds__(256) void convert_split(
    const float* __restrict__ src, ushort_t* __restrict__ dst)
{
  const int t    = blockIdx.x * 256 + threadIdx.x;
  const int lane = t & 63;
  const int blk  = t >> 6;            // rt*16 + ks
  const int rt   = blk >> 4, ks = blk & 15;
  const int row  = rt * 16 + (lane & 15);
  const int k    = ks * 32 + (lane >> 4) * 8;

  const float* s = src + (size_t)row * 512 + k;
  float4 a = *(const float4*)s, b = *(const float4*)(s + 4);
  float xs[8] = {a.x, a.y, a.z, a.w, b.x, b.y, b.z, b.w};
  uint4 hi, lo; split8(xs, hi, lo);

  ushort_t* d = dst + (size_t)blk * 1024 + lane * 8;
  *(uint4*)d = hi;
  *(uint4*)(d + 512) = lo;
}

// ---------------------------------------------------------------------------
// bf16x3 MFMA GEMM: C[M x Ncols] = A[M x 512] * W[Ncols x 512]^T + bias.
// A pre-converted (fragment-tiled split bf16), W converted inline.
// Block: 128x128 C tile, 256 threads = 4 waves in 2x2; wave = 64x64 =
// 4x4 MFMA 16x16x32 tiles; 3 MFMAs (hh, lh, hl) per tile per K32 step.
// LDS 32 KB. SCATTER writes qkv into q/k/v [B,H,N,HD].
// ---------------------------------------------------------------------------
template<bool SCATTER>
__global__ __launch_bounds__(256) void gemm_x3(
    const ushort_t* __restrict__ Ac, const float* __restrict__ W,
    const float* __restrict__ bias, float* __restrict__ C, int Ncols,
    float* __restrict__ qb, float* __restrict__ kb, float* __restrict__ vb)
{
  __shared__ ushort_t Ablk[8 * 1024];   // [rt][hi 512 | lo 512]
  __shared__ ushort_t Bblk[8 * 1024];

  const int t    = threadIdx.x;
  const int lane = t & 63, w = t >> 6;
  const int wr   = w >> 1, wc = w & 1;
  const int j0   = blockIdx.x * 128, i0 = blockIdx.y * 128;
  const int srow = t >> 2, skc = t & 3;     // W staging: 4 threads/row

  f32x4 acc[4][4];
#pragma unroll
  for (int a = 0; a < 4; ++a)
#pragma unroll
    for (int b = 0; b < 4; ++b) acc[a][b] = (f32x4){0.f, 0.f, 0.f, 0.f};

  for (int kt = 0; kt < 16; ++kt) {
    __syncthreads();
    // ---- stage A: copy 16 x 1KB pre-converted chunks ----
#pragma unroll
    for (int i = 0; i < 4; ++i) {
      const int c = w * 4 + i, rt = c >> 1, hl = c & 1;
      const size_t goff =
          ((size_t)((i0 >> 4) + rt) * 16 + kt) * 1024 + hl * 512 + lane * 8;
      *(uint4*)&Ablk[rt * 1024 + hl * 512 + lane * 8] = *(const uint4*)&Ac[goff];
    }
    // ---- stage B: load + split-convert W tile (128 rows x 32 k) ----
#pragma unroll
    for (int p = 0; p < 2; ++p) {
      const int row = p * 64 + srow;
      const float* s = W + (size_t)(j0 + row) * 512 + kt * 32 + skc * 8;
      float4 w0 = *(const float4*)s, w1 = *(const float4*)(s + 4);
      float xs[8] = {w0.x, w0.y, w0.z, w0.w, w1.x, w1.y, w1.z, w1.w};
      uint4 hi, lo; split8(xs, hi, lo);
      ushort_t* d = &Bblk[(row >> 4) * 1024 + ((row & 15) + 16 * skc) * 8];
      *(uint4*)d = hi;
      *(uint4*)(d + 512) = lo;
    }
    __syncthreads();

    // ---- fragments + MFMA ----
    const ushort_t* Ab = &Ablk[(wr * 4) * 1024 + lane * 8];
    const ushort_t* Bb = &Bblk[(wc * 4) * 1024 + lane * 8];
    short8 Ah[4], Al[4];
#pragma unroll
    for (int ti = 0; ti < 4; ++ti) {
      Ah[ti] = *(const short8*)(Ab + ti * 1024);
      Al[ti] = *(const short8*)(Ab + ti * 1024 + 512);
    }
#pragma unroll
    for (int ct = 0; ct < 4; ++ct) {
      short8 Bh = *(const short8*)(Bb + ct * 1024);
      short8 Bl = *(const short8*)(Bb + ct * 1024 + 512);
#pragma unroll
      for (int ti = 0; ti < 4; ++ti) {
        acc[ti][ct] = __builtin_amdgcn_mfma_f32_16x16x32_bf16(Ah[ti], Bh, acc[ti][ct], 0, 0, 0);
        acc[ti][ct] = __builtin_amdgcn_mfma_f32_16x16x32_bf16(Al[ti], Bh, acc[ti][ct], 0, 0, 0);
        acc[ti][ct] = __builtin_amdgcn_mfma_f32_16x16x32_bf16(Ah[ti], Bl, acc[ti][ct], 0, 0, 0);
      }
    }
  }

  // ---- epilogue: C/D layout col=lane&15, row=(lane>>4)*4+reg ----
  const int rbase = i0 + wr * 64 + (lane >> 4) * 4;
  const int cbase = j0 + wc * 64 + (lane & 15);
#pragma unroll
  for (int ct = 0; ct < 4; ++ct) {
    const int col = cbase + ct * 16;
    const float bv = bias[col];
    float* dst = nullptr; int dcol = col;
    if (SCATTER) {
      const int s = col >> 9, h = (col >> 6) & 7;
      dst  = (s == 0) ? qb : (s == 1) ? kb : vb;
      dcol = col & 63;
      dst += (size_t)h * Nn * HD + dcol;  // + (b2*8h..) per row below
    }
#pragma unroll
    for (int ti = 0; ti < 4; ++ti) {
      const int r0 = rbase + ti * 16;
#pragma unroll
      for (int r = 0; r < 4; ++r) {
        const float v = acc[ti][ct][r] + bv;
        const int row = r0 + r;
        if (SCATTER) {
          const int b2 = row >> 10, n = row & 1023;
          dst[((size_t)b2 * Hh * Nn + n) * HD] = v;
        } else {
          C[(size_t)row * Ncols + col] = v;
        }
      }
    }
  }
}

// ---------------------------------------------------------------------------
// Flash-style attention (unchanged from R2): one block = (b,h) x 64-q tile.
// ---------------------------------------------------------------------------
__global__ __launch_bounds__(256) void attn_k(
    const float* __restrict__ qg, const float* __restrict__ kg,
    const float* __restrict__ vg, const float* __restrict__ bias,
    const unsigned char* __restrict__ m8, float* __restrict__ outp)
{
  __shared__ float Qst[64][68];
  __shared__ float KP[64][68];
  __shared__ float Vst[64][68];

  const int t  = threadIdx.x;
  const int tx = t & 15;
  const int ty = t >> 4;
  const int bx = blockIdx.x;
  const int qt = bx & 15;
  const int bh = bx >> 4;
  const int b  = bh >> 3;
  const int h  = bh & 7;
  const int q0 = qt * 64;
  const bool bytelay = (m8[1] != 0);

#pragma unroll
  for (int i = 0; i < 4; ++i) {
    const int idx = i * 256 + t;
    const int qq  = idx >> 4;
    const int d4  = (idx & 15) * 4;
    float4 v = *(const float4*)&qg[((size_t)bh * Nn + q0 + qq) * HD + d4];
    Qst[d4 + 0][qq] = v.x; Qst[d4 + 1][qq] = v.y;
    Qst[d4 + 2][qq] = v.z; Qst[d4 + 3][qq] = v.w;
  }

  float O[4][4];
  float m_run[4], l_run[4];
#pragma unroll
  for (int ii = 0; ii < 4; ++ii) {
    m_run[ii] = -__builtin_inff(); l_run[ii] = 0.f;
#pragma unroll
    for (int jj = 0; jj < 4; ++jj) O[ii][jj] = 0.f;
  }

  for (int kt = 0; kt < 16; ++kt) {
    bool kv[4]; int any = 0;
#pragma unroll
    for (int jj = 0; jj < 4; ++jj) {
      kv[jj] = lane_valid(m8, bytelay, b * Nn + kt * 64 + 4 * tx + jj);
      any |= (int)kv[jj];
    }
    if (!__syncthreads_or(any)) continue;

#pragma unroll
    for (int i = 0; i < 4; ++i) {
      const int idx = i * 256 + t;
      const int kk  = idx >> 4;
      const int d4  = (idx & 15) * 4;
      float4 kvv = *(const float4*)&kg[((size_t)bh * Nn + kt * 64 + kk) * HD + d4];
      KP[d4 + 0][kk] = kvv.x; KP[d4 + 1][kk] = kvv.y;
      KP[d4 + 2][kk] = kvv.z; KP[d4 + 3][kk] = kvv.w;
      *(float4*)&Vst[kk][d4] =
          *(const float4*)&vg[((size_t)bh * Nn + kt * 64 + kk) * HD + d4];
    }
    __syncthreads();

    float4 bias4[4];
#pragma unroll
    for (int ii = 0; ii < 4; ++ii)
      bias4[ii] = *(const float4*)
          &bias[((size_t)bh * Nn + q0 + 4 * ty + ii) * Nn + kt * 64 + 4 * tx];

    float S[4][4];
#pragma unroll
    for (int ii = 0; ii < 4; ++ii)
#pragma unroll
      for (int jj = 0; jj < 4; ++jj) S[ii][jj] = 0.f;
#pragma unroll 4
    for (int d = 0; d < 64; ++d) {
      float4 q4 = *(const float4*)&Qst[d][4 * ty];
      float4 k4 = *(const float4*)&KP[d][4 * tx];
      float qa[4] = {q4.x, q4.y, q4.z, q4.w};
      float ka[4] = {k4.x, k4.y, k4.z, k4.w};
#pragma unroll
      for (int ii = 0; ii < 4; ++ii)
#pragma unroll
        for (int jj = 0; jj < 4; ++jj)
          S[ii][jj] += qa[ii] * ka[jj];
    }

    float mt[4];
#pragma unroll
    for (int ii = 0; ii < 4; ++ii) {
      float bb[4] = {bias4[ii].x, bias4[ii].y, bias4[ii].z, bias4[ii].w};
      float m = -__builtin_inff();
#pragma unroll
      for (int jj = 0; jj < 4; ++jj) {
        float s = kv[jj] ? S[ii][jj] * SCALE + bb[jj] : -__builtin_inff();
        S[ii][jj] = s;
        m = fmaxf(m, s);
      }
      mt[ii] = m;
    }
#pragma unroll
    for (int off = 1; off < 16; off <<= 1)
#pragma unroll
      for (int ii = 0; ii < 4; ++ii)
        mt[ii] = fmaxf(mt[ii], __shfl_xor(mt[ii], off));

    float alpha[4], lt[4];
#pragma unroll
    for (int ii = 0; ii < 4; ++ii) {
      float mn = fmaxf(m_run[ii], mt[ii]);
      alpha[ii] = __expf(m_run[ii] - mn);
      m_run[ii] = mn;
      float l = 0.f;
#pragma unroll
      for (int jj = 0; jj < 4; ++jj) {
        float p = __expf(S[ii][jj] - mn);
        S[ii][jj] = p;
        l += p;
      }
      lt[ii] = l;
    }
#pragma unroll
    for (int off = 1; off < 16; off <<= 1)
#pragma unroll
      for (int ii = 0; ii < 4; ++ii)
        lt[ii] += __shfl_xor(lt[ii], off);
#pragma unroll
    for (int ii = 0; ii < 4; ++ii) {
      l_run[ii] = l_run[ii] * alpha[ii] + lt[ii];
#pragma unroll
      for (int jj = 0; jj < 4; ++jj) O[ii][jj] *= alpha[ii];
    }

    __syncthreads();
#pragma unroll
    for (int jj = 0; jj < 4; ++jj) {
      float4 p4; p4.x = S[0][jj]; p4.y = S[1][jj]; p4.z = S[2][jj]; p4.w = S[3][jj];
      *(float4*)&KP[4 * tx + jj][4 * ty] = p4;
    }
    __syncthreads();

#pragma unroll 4
    for (int k = 0; k < 64; ++k) {
      float4 p4 = *(const float4*)&KP[k][4 * ty];
      float4 v4 = *(const float4*)&Vst[k][4 * tx];
      float pa[4] = {p4.x, p4.y, p4.z, p4.w};
      float va[4] = {v4.x, v4.y, v4.z, v4.w};
#pragma unroll
      for (int ii = 0; ii < 4; ++ii)
#pragma unroll
        for (int jj = 0; jj < 4; ++jj)
          O[ii][jj] += pa[ii] * va[jj];
    }
  }

#pragma unroll
  for (int ii = 0; ii < 4; ++ii) {
    const int q = q0 + 4 * ty + ii;
    const bool vq = lane_valid(m8, bytelay, b * Nn + q);
    const float r = (vq && l_run[ii] > 0.f) ? (1.f / l_run[ii]) : 0.f;
    float4 o;
    o.x = O[ii][0] * r; o.y = O[ii][1] * r;
    o.z = O[ii][2] * r; o.w = O[ii][3] * r;
    *(float4*)&outp[((size_t)(b * Nn + q)) * Dd + h * HD + 4 * tx] = o;
  }
}

// ---------------------------------------------------------------------------
extern "C" void kernel_launch(void* const* d_in, const int* in_sizes, int n_in,
                              void* d_out, int out_size, void* d_ws, size_t ws_size,
                              hipStream_t stream) {
  const float* x        = (const float*)d_in[0];
  const unsigned char* mask8 = (const unsigned char*)d_in[1];
  const float* attnbias = (const float*)d_in[2];
  const float* qkv_w    = (const float*)d_in[3];
  const float* qkv_b    = (const float*)d_in[4];
  const float* out_w    = (const float*)d_in[5];
  const float* out_b    = (const float*)d_in[6];
  float* out = (float*)d_out;

  // Workspace (64 MB, regions reused across phases):
  // [0,16M):  x_conv (phase 1)  -> aout fp32 (phase 2, x_conv dead)
  // [16,32M): qbuf              -> aout_conv (phase 3, qbuf dead)
  // [32,48M): kbuf
  // [48,64M): vbuf
  float* ws = (float*)d_ws;
  const size_t SEG = (size_t)Bc * Hh * Nn * HD;   // 4M floats = 16 MB
  ushort_t* x_conv    = (ushort_t*)ws;
  float*    qbuf      = ws + SEG;
  float*    kbuf      = ws + 2 * SEG;
  float*    vbuf      = ws + 3 * SEG;
  float*    aout      = ws;                        // reuses x_conv region
  ushort_t* aout_conv = (ushort_t*)(ws + SEG);     // reuses qbuf region

  // 1) convert x -> fragment-tiled split bf16
  convert_split<<<8192 * 64 / 256, 256, 0, stream>>>(x, x_conv);

  // 2) QKV projection (bf16x3 MFMA), scatter into q/k/v [B,H,N,HD]
  gemm_x3<true><<<dim3(1536 / 128, 8192 / 128), 256, 0, stream>>>(
      x_conv, qkv_w, qkv_b, nullptr, 1536, qbuf, kbuf, vbuf);

  // 3) attention -> aout [B,N,D] fp32
  attn_k<<<dim3(Bc * Hh * (Nn / 64)), 256, 0, stream>>>(
      qbuf, kbuf, vbuf, attnbias, mask8, aout);

  // 4) convert attention output
  convert_split<<<8192 * 64 / 256, 256, 0, stream>>>(aout, aout_conv);

  // 5) output projection (bf16x3 MFMA) -> d_out
  gemm_x3<false><<<dim3(512 / 128, 8192 / 128), 256, 0, stream>>>(
      aout_conv, out_w, out_b, out, 512, nullptr, nullptr, nullptr);
}

// Round 4
// 566.891 us; speedup vs baseline: 2.6410x; 1.1504x over previous
//
#include <hip/hip_runtime.h>
#include <math.h>

// Problem constants
constexpr int Bc  = 8;
constexpr int Nn  = 1024;
constexpr int Dd  = 512;
constexpr int Hh  = 8;
constexpr int HD  = 64;
constexpr float SCALE = 0.125f; // 1/sqrt(64)

typedef unsigned short ushort_t;
typedef unsigned int uint32;
typedef __attribute__((ext_vector_type(8))) short short8;   // 8 bf16 (4 VGPRs)
typedef __attribute__((ext_vector_type(4))) float f32x4;

// ---------------- bf16 split helpers (round-to-nearest-even) ----------------
__device__ __forceinline__ uint32 bf16rn(float x) {
  uint32 u = __float_as_uint(x);
  return (u + 0x7FFFu + ((u >> 16) & 1u)) >> 16;
}
__device__ __forceinline__ float bf16up(uint32 h) { return __uint_as_float(h << 16); }

__device__ __forceinline__ void split8(const float* xs, uint4& hi, uint4& lo) {
  uint32 h[8], l[8];
#pragma unroll
  for (int j = 0; j < 8; ++j) {
    h[j] = bf16rn(xs[j]);
    l[j] = bf16rn(xs[j] - bf16up(h[j]));
  }
  hi.x = h[0] | (h[1] << 16); hi.y = h[2] | (h[3] << 16);
  hi.z = h[4] | (h[5] << 16); hi.w = h[6] | (h[7] << 16);
  lo.x = l[0] | (l[1] << 16); lo.y = l[2] | (l[3] << 16);
  lo.z = l[4] | (l[5] << 16); lo.w = l[6] | (l[7] << 16);
}

// node_valid_mask may arrive as 1-byte bool or 4-byte int/float.
__device__ __forceinline__ bool lane_valid(const unsigned char* m8, bool bytelay, int idx) {
  if (bytelay) return m8[idx] != 0;
  return ((const int*)m8)[idx] != 0;
}

// ---------------------------------------------------------------------------
// Convert fp32 [R][512] -> MFMA-fragment-tiled split bf16 (K=512 GEMM A-side):
// layout [R/16][16 ksteps][2 hi/lo][512] ushort.
// ---------------------------------------------------------------------------
__global__ __launch_bounds__(256) void convert_split(
    const float* __restrict__ src, ushort_t* __restrict__ dst)
{
  const int t    = blockIdx.x * 256 + threadIdx.x;
  const int lane = t & 63;
  const int blk  = t >> 6;            // rt*16 + ks
  const int rt   = blk >> 4, ks = blk & 15;
  const int row  = rt * 16 + (lane & 15);
  const int k    = ks * 32 + (lane >> 4) * 8;

  const float* s = src + (size_t)row * 512 + k;
  float4 a = *(const float4*)s, b = *(const float4*)(s + 4);
  float xs[8] = {a.x, a.y, a.z, a.w, b.x, b.y, b.z, b.w};
  uint4 hi, lo; split8(xs, hi, lo);

  ushort_t* d = dst + (size_t)blk * 1024 + lane * 8;
  *(uint4*)d = hi;
  *(uint4*)(d + 512) = lo;
}

// ---------------------------------------------------------------------------
// Convert q/k fp32 [rows][64] (rows = bh*1024 + token) into A/B-operand
// fragment tiles: [rows/16][2 ks][2 hl][512] ushort.
// Lane l of frag (tile,ks) holds src[tile*16 + (l&15)][ks*32 + (l>>4)*8 + j].
// ---------------------------------------------------------------------------
__global__ __launch_bounds__(256) void convert_frag_qk(
    const float* __restrict__ src, ushort_t* __restrict__ dst)
{
  const int t    = blockIdx.x * 256 + threadIdx.x;
  const int lane = t & 63;
  const int fid  = t >> 6;           // tile*2 + ks
  const int tile = fid >> 1, ks = fid & 1;
  const int row  = tile * 16 + (lane & 15);
  const int d    = ks * 32 + (lane >> 4) * 8;

  const float* s = src + (size_t)row * HD + d;
  float4 a = *(const float4*)s, b = *(const float4*)(s + 4);
  float xs[8] = {a.x, a.y, a.z, a.w, b.x, b.y, b.z, b.w};
  uint4 hi, lo; split8(xs, hi, lo);

  ushort_t* dp = dst + (size_t)fid * 1024 + lane * 8;
  *(uint4*)dp = hi;
  *(uint4*)(dp + 512) = lo;
}

// ---------------------------------------------------------------------------
// Convert v fp32 [bh][1024 key][64 d] into PV B-operand fragments:
// [bh][16 kt][2 ks][4 dt][2 hl][512]. Lane l of frag holds
// v[key = kt*64 + ks*32 + (l>>4)*8 + j][d = dt*16 + (l&15)].
// ---------------------------------------------------------------------------
__global__ __launch_bounds__(256) void convert_frag_v(
    const float* __restrict__ src, ushort_t* __restrict__ dst)
{
  const int t    = blockIdx.x * 256 + threadIdx.x;
  const int lane = t & 63;
  const int fid  = t >> 6;           // ((bh*16+kt)*2+ks)*4+dt
  const int dt   = fid & 3;
  const int ks   = (fid >> 2) & 1;
  const int kt   = (fid >> 3) & 15;
  const int bh   = fid >> 7;
  const int d    = dt * 16 + (lane & 15);
  const int key0 = kt * 64 + ks * 32 + (lane >> 4) * 8;

  const float* s = src + ((size_t)bh * Nn + key0) * HD + d;
  float xs[8];
#pragma unroll
  for (int j = 0; j < 8; ++j) xs[j] = s[(size_t)j * HD];
  uint4 hi, lo; split8(xs, hi, lo);

  ushort_t* dp = dst + (size_t)fid * 1024 + lane * 8;
  *(uint4*)dp = hi;
  *(uint4*)(dp + 512) = lo;
}

// ---------------------------------------------------------------------------
// bf16x3 MFMA GEMM (unchanged from R3): C = A[Mx512] * W[Ncolsx512]^T + bias.
// ---------------------------------------------------------------------------
template<bool SCATTER>
__global__ __launch_bounds__(256) void gemm_x3(
    const ushort_t* __restrict__ Ac, const float* __restrict__ W,
    const float* __restrict__ bias, float* __restrict__ C, int Ncols,
    float* __restrict__ qb, float* __restrict__ kb, float* __restrict__ vb)
{
  __shared__ ushort_t Ablk[8 * 1024];
  __shared__ ushort_t Bblk[8 * 1024];

  const int t    = threadIdx.x;
  const int lane = t & 63, w = t >> 6;
  const int wr   = w >> 1, wc = w & 1;
  const int j0   = blockIdx.x * 128, i0 = blockIdx.y * 128;
  const int srow = t >> 2, skc = t & 3;

  f32x4 acc[4][4];
#pragma unroll
  for (int a = 0; a < 4; ++a)
#pragma unroll
    for (int b = 0; b < 4; ++b) acc[a][b] = (f32x4){0.f, 0.f, 0.f, 0.f};

  for (int kt = 0; kt < 16; ++kt) {
    __syncthreads();
#pragma unroll
    for (int i = 0; i < 4; ++i) {
      const int c = w * 4 + i, rt = c >> 1, hl = c & 1;
      const size_t goff =
          ((size_t)((i0 >> 4) + rt) * 16 + kt) * 1024 + hl * 512 + lane * 8;
      *(uint4*)&Ablk[rt * 1024 + hl * 512 + lane * 8] = *(const uint4*)&Ac[goff];
    }
#pragma unroll
    for (int p = 0; p < 2; ++p) {
      const int row = p * 64 + srow;
      const float* s = W + (size_t)(j0 + row) * 512 + kt * 32 + skc * 8;
      float4 w0 = *(const float4*)s, w1 = *(const float4*)(s + 4);
      float xs[8] = {w0.x, w0.y, w0.z, w0.w, w1.x, w1.y, w1.z, w1.w};
      uint4 hi, lo; split8(xs, hi, lo);
      ushort_t* d = &Bblk[(row >> 4) * 1024 + ((row & 15) + 16 * skc) * 8];
      *(uint4*)d = hi;
      *(uint4*)(d + 512) = lo;
    }
    __syncthreads();

    const ushort_t* Ab = &Ablk[(wr * 4) * 1024 + lane * 8];
    const ushort_t* Bb = &Bblk[(wc * 4) * 1024 + lane * 8];
    short8 Ah[4], Al[4];
#pragma unroll
    for (int ti = 0; ti < 4; ++ti) {
      Ah[ti] = *(const short8*)(Ab + ti * 1024);
      Al[ti] = *(const short8*)(Ab + ti * 1024 + 512);
    }
#pragma unroll
    for (int ct = 0; ct < 4; ++ct) {
      short8 Bh = *(const short8*)(Bb + ct * 1024);
      short8 Bl = *(const short8*)(Bb + ct * 1024 + 512);
#pragma unroll
      for (int ti = 0; ti < 4; ++ti) {
        acc[ti][ct] = __builtin_amdgcn_mfma_f32_16x16x32_bf16(Ah[ti], Bh, acc[ti][ct], 0, 0, 0);
        acc[ti][ct] = __builtin_amdgcn_mfma_f32_16x16x32_bf16(Al[ti], Bh, acc[ti][ct], 0, 0, 0);
        acc[ti][ct] = __builtin_amdgcn_mfma_f32_16x16x32_bf16(Ah[ti], Bl, acc[ti][ct], 0, 0, 0);
      }
    }
  }

  const int rbase = i0 + wr * 64 + (lane >> 4) * 4;
  const int cbase = j0 + wc * 64 + (lane & 15);
#pragma unroll
  for (int ct = 0; ct < 4; ++ct) {
    const int col = cbase + ct * 16;
    const float bv = bias[col];
    float* dst = nullptr;
    if (SCATTER) {
      const int s = col >> 9, h = (col >> 6) & 7;
      dst  = (s == 0) ? qb : (s == 1) ? kb : vb;
      dst += (size_t)h * Nn * HD + (col & 63);
    }
#pragma unroll
    for (int ti = 0; ti < 4; ++ti) {
      const int r0 = rbase + ti * 16;
#pragma unroll
      for (int r = 0; r < 4; ++r) {
        const float v = acc[ti][ct][r] + bv;
        const int row = r0 + r;
        if (SCATTER) {
          const int b2 = row >> 10, n = row & 1023;
          dst[((size_t)b2 * Hh * Nn + n) * HD] = v;
        } else {
          C[(size_t)row * Ncols + col] = v;
        }
      }
    }
  }
}

// ---------------------------------------------------------------------------
// MFMA flash attention. Block = (bh, 64-q tile); 4 independent waves, each
// owning 16 queries. No __syncthreads. Per 64-key tile: S = Q*K^T via x3
// split-bf16 MFMA (frags read straight from pre-converted global buffers),
// register online-softmax (C/D layout: 4 rows/lane), P transposed to
// A-fragment layout via per-wave 4 KB LDS scatter, then O += P*V (x3).
// ---------------------------------------------------------------------------
__global__ __launch_bounds__(256) void attn_mfma(
    const ushort_t* __restrict__ qf, const ushort_t* __restrict__ kf,
    const ushort_t* __restrict__ vf, const float* __restrict__ bias,
    const unsigned char* __restrict__ m8, float* __restrict__ outp)
{
  __shared__ ushort_t Pbuf[4][2048];   // per-wave [ks][hl][512]

  const int t    = threadIdx.x;
  const int lane = t & 63, w = t >> 6;
  const int bx   = blockIdx.x;
  const int qt   = bx & 15;
  const int bh   = bx >> 4;
  const int b    = bh >> 3, h = bh & 7;
  const int tt   = qt * 4 + w;         // 16-query tile within (bh): 0..63
  const int q0   = tt * 16;
  const bool bytelay = (m8[1] != 0);

  // Q fragments (held for the whole kernel)
  short8 Qh[2], Ql[2];
#pragma unroll
  for (int ks = 0; ks < 2; ++ks) {
    const ushort_t* qp = qf + ((size_t)(bh * 64 + tt) * 2 + ks) * 1024 + lane * 8;
    Qh[ks] = *(const short8*)qp;
    Ql[ks] = *(const short8*)(qp + 512);
  }

  f32x4 Oacc[4];
#pragma unroll
  for (int dt = 0; dt < 4; ++dt) Oacc[dt] = (f32x4){0.f, 0.f, 0.f, 0.f};
  float m_run[4], l_run[4];
#pragma unroll
  for (int r = 0; r < 4; ++r) { m_run[r] = -__builtin_inff(); l_run[r] = 0.f; }

  ushort_t* pb = &Pbuf[w][0];

  for (int kt = 0; kt < 16; ++kt) {
    // key validity: lane i <-> key kt*64+i
    const bool kvme = lane_valid(m8, bytelay, b * Nn + kt * 64 + lane);
    const unsigned long long kmask = __ballot(kvme);
    if (kmask == 0ull) continue;       // wave-uniform

    // bias prefetch: 16 scalars (row q0+(lane>>4)*4+r, col kt*64+nt*16+(lane&15))
    const float* bp = bias + ((size_t)bh * Nn + q0 + (lane >> 4) * 4) * Nn
                           + kt * 64 + (lane & 15);
    float bias_v[4][4];
#pragma unroll
    for (int r = 0; r < 4; ++r)
#pragma unroll
      for (int nt = 0; nt < 4; ++nt)
        bias_v[nt][r] = bp[(size_t)r * Nn + nt * 16];

    // S = Q*K^T (x3)
    f32x4 Sacc[4];
#pragma unroll
    for (int nt = 0; nt < 4; ++nt) Sacc[nt] = (f32x4){0.f, 0.f, 0.f, 0.f};
#pragma unroll
    for (int ks = 0; ks < 2; ++ks)
#pragma unroll
      for (int nt = 0; nt < 4; ++nt) {
        const ushort_t* kp =
            kf + ((size_t)(bh * 64 + kt * 4 + nt) * 2 + ks) * 1024 + lane * 8;
        short8 Kh = *(const short8*)kp;
        short8 Kl = *(const short8*)(kp + 512);
        Sacc[nt] = __builtin_amdgcn_mfma_f32_16x16x32_bf16(Qh[ks], Kh, Sacc[nt], 0, 0, 0);
        Sacc[nt] = __builtin_amdgcn_mfma_f32_16x16x32_bf16(Ql[ks], Kh, Sacc[nt], 0, 0, 0);
        Sacc[nt] = __builtin_amdgcn_mfma_f32_16x16x32_bf16(Qh[ks], Kl, Sacc[nt], 0, 0, 0);
      }

    // scale + bias + key mask; tile row-max
    float Sv[4][4];
    float mt[4] = {-__builtin_inff(), -__builtin_inff(), -__builtin_inff(), -__builtin_inff()};
#pragma unroll
    for (int nt = 0; nt < 4; ++nt) {
      const bool kv = (kmask >> (nt * 16 + (lane & 15))) & 1ull;
#pragma unroll
      for (int r = 0; r < 4; ++r) {
        float s = kv ? Sacc[nt][r] * SCALE + bias_v[nt][r] : -__builtin_inff();
        Sv[nt][r] = s;
        mt[r] = fmaxf(mt[r], s);
      }
    }
#pragma unroll
    for (int off = 1; off < 16; off <<= 1)
#pragma unroll
      for (int r = 0; r < 4; ++r) mt[r] = fmaxf(mt[r], __shfl_xor(mt[r], off));

    // online-softmax update + P split-bf16 scatter into per-wave LDS frags
    float alpha[4], lt[4];
#pragma unroll
    for (int r = 0; r < 4; ++r) {
      const float mn = fmaxf(m_run[r], mt[r]);
      alpha[r] = __expf(m_run[r] - mn);
      m_run[r] = mn;
      lt[r] = 0.f;
    }
#pragma unroll
    for (int nt = 0; nt < 4; ++nt) {
      const int ksp    = nt >> 1;
      const int key_in = (nt & 1) * 16 + (lane & 15);   // key & 31
      const int lane_p = 16 * (key_in >> 3);
      const int j      = key_in & 7;
#pragma unroll
      for (int r = 0; r < 4; ++r) {
        const float p = __expf(Sv[nt][r] - m_run[r]);
        lt[r] += p;
        const uint32 ph = bf16rn(p);
        const uint32 pl = bf16rn(p - bf16up(ph));
        const int lp = ((lane >> 4) * 4 + r) + lane_p;
        pb[(ksp * 2 + 0) * 512 + lp * 8 + j] = (ushort_t)ph;
        pb[(ksp * 2 + 1) * 512 + lp * 8 + j] = (ushort_t)pl;
      }
    }
#pragma unroll
    for (int off = 1; off < 16; off <<= 1)
#pragma unroll
      for (int r = 0; r < 4; ++r) lt[r] += __shfl_xor(lt[r], off);
#pragma unroll
    for (int r = 0; r < 4; ++r) l_run[r] = l_run[r] * alpha[r] + lt[r];
#pragma unroll
    for (int dt = 0; dt < 4; ++dt)
#pragma unroll
      for (int r = 0; r < 4; ++r) Oacc[dt][r] *= alpha[r];

    // read P fragments (wave-local; compiler inserts lgkmcnt wait)
    short8 Ph[2], Pl[2];
#pragma unroll
    for (int ks = 0; ks < 2; ++ks) {
      Ph[ks] = *(const short8*)&pb[(ks * 2 + 0) * 512 + lane * 8];
      Pl[ks] = *(const short8*)&pb[(ks * 2 + 1) * 512 + lane * 8];
    }

    // O += P*V (x3)
#pragma unroll
    for (int dt = 0; dt < 4; ++dt)
#pragma unroll
      for (int ks = 0; ks < 2; ++ks) {
        const ushort_t* vp =
            vf + ((size_t)(((bh * 16 + kt) * 2 + ks) * 4 + dt)) * 1024 + lane * 8;
        short8 Vh = *(const short8*)vp;
        short8 Vl = *(const short8*)(vp + 512);
        Oacc[dt] = __builtin_amdgcn_mfma_f32_16x16x32_bf16(Ph[ks], Vh, Oacc[dt], 0, 0, 0);
        Oacc[dt] = __builtin_amdgcn_mfma_f32_16x16x32_bf16(Pl[ks], Vh, Oacc[dt], 0, 0, 0);
        Oacc[dt] = __builtin_amdgcn_mfma_f32_16x16x32_bf16(Ph[ks], Vl, Oacc[dt], 0, 0, 0);
      }
  }

  // epilogue: normalize; invalid/fully-masked queries -> 0 (nan_to_num)
#pragma unroll
  for (int r = 0; r < 4; ++r) {
    const int q = q0 + (lane >> 4) * 4 + r;
    const bool vq = lane_valid(m8, bytelay, b * Nn + q);
    const float rinv = (vq && l_run[r] > 0.f) ? (1.f / l_run[r]) : 0.f;
    float* op = outp + ((size_t)(b * Nn + q)) * Dd + h * HD + (lane & 15);
#pragma unroll
    for (int dt = 0; dt < 4; ++dt) op[dt * 16] = Oacc[dt][r] * rinv;
  }
}

// ---------------------------------------------------------------------------
extern "C" void kernel_launch(void* const* d_in, const int* in_sizes, int n_in,
                              void* d_out, int out_size, void* d_ws, size_t ws_size,
                              hipStream_t stream) {
  const float* x        = (const float*)d_in[0];
  const unsigned char* mask8 = (const unsigned char*)d_in[1];
  const float* attnbias = (const float*)d_in[2];
  const float* qkv_w    = (const float*)d_in[3];
  const float* qkv_b    = (const float*)d_in[4];
  const float* out_w    = (const float*)d_in[5];
  const float* out_b    = (const float*)d_in[6];
  float* out = (float*)d_out;

  // 64 MB workspace, 4 x 16 MB regions A/B/C/D, recycled:
  //  A: x_conv -> qf -> aout_conv     B: q fp32 -> kf
  //  C: k fp32 -> vf                  D: v fp32 -> aout fp32
  float* ws = (float*)d_ws;
  const size_t SEG = (size_t)Bc * Hh * Nn * HD;   // 4M floats = 16 MB
  float* A = ws;
  float* B = ws + SEG;
  float* C = ws + 2 * SEG;
  float* D = ws + 3 * SEG;

  ushort_t* x_conv    = (ushort_t*)A;
  float*    qbuf      = B;
  float*    kbuf      = C;
  float*    vbuf      = D;
  ushort_t* qfrag     = (ushort_t*)A;   // after x_conv is dead
  ushort_t* kfrag     = (ushort_t*)B;   // after q fp32 is dead
  ushort_t* vfrag     = (ushort_t*)C;   // after k fp32 is dead
  float*    aout      = D;              // after v fp32 is dead
  ushort_t* aout_conv = (ushort_t*)A;   // after qfrag is dead

  // 1) convert x -> fragment-tiled split bf16
  convert_split<<<2048, 256, 0, stream>>>(x, x_conv);

  // 2) QKV projection (bf16x3 MFMA), scatter into q/k/v fp32 [B,H,N,HD]
  gemm_x3<true><<<dim3(12, 64), 256, 0, stream>>>(
      x_conv, qkv_w, qkv_b, nullptr, 1536, qbuf, kbuf, vbuf);

  // 3) convert q,k,v -> attention MFMA fragments (split bf16)
  convert_frag_qk<<<2048, 256, 0, stream>>>(qbuf, qfrag);  // q(B) -> A
  convert_frag_qk<<<2048, 256, 0, stream>>>(kbuf, kfrag);  // k(C) -> B
  convert_frag_v <<<2048, 256, 0, stream>>>(vbuf, vfrag);  // v(D) -> C

  // 4) MFMA flash attention -> aout fp32 [B,N,D] (region D)
  attn_mfma<<<1024, 256, 0, stream>>>(
      qfrag, kfrag, vfrag, attnbias, mask8, aout);

  // 5) convert attention output, 6) output projection
  convert_split<<<2048, 256, 0, stream>>>(aout, aout_conv);
  gemm_x3<false><<<dim3(4, 64), 256, 0, stream>>>(
      aout_conv, out_w, out_b, out, 512, nullptr, nullptr, nullptr);
}